// Round 1
// baseline (2417.934 us; speedup 1.0000x reference)
//
#include <hip/hip_runtime.h>
#include <math.h>

#define D 128
#define TROWS 64
#define NEG_SLOPE 0.2f
#define REG_LAMBDA 1e-4f
#define NORM_EPS 1e-12f

__device__ __forceinline__ float wave_red(float v){
  #pragma unroll
  for (int o = 32; o > 0; o >>= 1) v += __shfl_xor(v, o, 64);
  return v;
}

__global__ __launch_bounds__(256) void hist_kernel(const int* __restrict__ erow, int* __restrict__ counts, int nnz){
  int e = blockIdx.x*256 + threadIdx.x;
  if (e < nnz) atomicAdd(&counts[erow[e]], 1);
}

__global__ __launch_bounds__(1024) void scan1_kernel(const int* __restrict__ counts, int* __restrict__ rowptr, int* __restrict__ sums, int n){
  __shared__ int tmp[1024];
  int t = threadIdx.x; int i = blockIdx.x*1024 + t;
  int v = (i < n) ? counts[i] : 0;
  tmp[t] = v; __syncthreads();
  #pragma unroll
  for (int off = 1; off < 1024; off <<= 1){
    int a = (t >= off) ? tmp[t-off] : 0; __syncthreads();
    tmp[t] += a; __syncthreads();
  }
  if (i < n) rowptr[i] = tmp[t] - v;   // exclusive within block
  if (t == 1023) sums[blockIdx.x] = tmp[t];
}

__global__ __launch_bounds__(1024) void scan2_kernel(int* __restrict__ sums, int nb){
  __shared__ int tmp[1024];
  int t = threadIdx.x;
  int v = (t < nb) ? sums[t] : 0;
  tmp[t] = v; __syncthreads();
  #pragma unroll
  for (int off = 1; off < 1024; off <<= 1){
    int a = (t >= off) ? tmp[t-off] : 0; __syncthreads();
    tmp[t] += a; __syncthreads();
  }
  if (t < nb) sums[t] = tmp[t] - v;    // exclusive block offsets
}

__global__ __launch_bounds__(1024) void scan3_kernel(int* __restrict__ rowptr, const int* __restrict__ sums, int n, int nnz){
  int i = blockIdx.x*1024 + threadIdx.x;
  if (i < n) rowptr[i] += sums[blockIdx.x];
  if (i == 0) rowptr[n] = nnz;
}

__global__ __launch_bounds__(256) void scatter_kernel(const int* __restrict__ erow, const int* __restrict__ ecol,
                                                      const float* __restrict__ eval, int* __restrict__ cursor,
                                                      int* __restrict__ scol, float* __restrict__ sval, int nnz){
  int e = blockIdx.x*256 + threadIdx.x;
  if (e >= nnz) return;
  int r = erow[e];
  int p = atomicAdd(&cursor[r], 1);
  scol[p] = ecol[e]; sval[p] = eval[e];
}

// side[r] = sum_e val_e * ego[col_e] ; one wave per row, float2 per lane.
__global__ __launch_bounds__(256) void spmm_kernel(const int* __restrict__ rowptr, const int* __restrict__ scol,
                                                   const float* __restrict__ sval, const float* __restrict__ ego,
                                                   float* __restrict__ side, int n){
  int w = (blockIdx.x*256 + threadIdx.x) >> 6;
  int lane = threadIdx.x & 63;
  if (w >= n) return;
  int s = rowptr[w], e = rowptr[w+1];
  const float2* eg2 = (const float2*)ego;
  float2 acc = make_float2(0.f, 0.f);
  int i = s;
  for (; i + 1 < e; i += 2){
    int   c0 = scol[i],  c1 = scol[i+1];
    float v0 = sval[i],  v1 = sval[i+1];
    float2 x0 = eg2[(size_t)c0*64 + lane];
    float2 x1 = eg2[(size_t)c1*64 + lane];
    acc.x += v0*x0.x + v1*x1.x;
    acc.y += v0*x0.y + v1*x1.y;
  }
  if (i < e){
    int c0 = scol[i]; float v0 = sval[i];
    float2 x0 = eg2[(size_t)c0*64 + lane];
    acc.x += v0*x0.x; acc.y += v0*x0.y;
  }
  ((float2*)side)[(size_t)w*64 + lane] = acc;
}

// ego[r] = leaky( side[r]@W1 + (ego[r].*side[r])@W2 + b1 + b2 ), in place.
// Block = 4 waves × 16 rows; W rows streamed from L1, (s,p) staged in LDS.
__global__ __launch_bounds__(256) void transform_kernel(const float* __restrict__ side, float* __restrict__ ego,
                                                        const float* __restrict__ W1, const float* __restrict__ W2,
                                                        const float* __restrict__ b1, const float* __restrict__ b2, int n){
  __shared__ float2 SP[TROWS][D];   // 64 KiB: (s, s*e) per element
  int row0 = blockIdx.x * TROWS;
  for (int idx = threadIdx.x; idx < TROWS*D; idx += 256){
    int r = idx >> 7, c = idx & 127;
    int row = row0 + r;
    float s = 0.f, p = 0.f;
    if (row < n){
      s = side[(size_t)row*D + c];
      p = s * ego[(size_t)row*D + c];
    }
    SP[r][c] = make_float2(s, p);
  }
  __syncthreads();
  int wave = threadIdx.x >> 6, lane = threadIdx.x & 63;
  int wr0 = wave * 16;
  float acc0[16], acc1[16];
  #pragma unroll
  for (int r = 0; r < 16; r++){ acc0[r] = 0.f; acc1[r] = 0.f; }
  #pragma unroll 2
  for (int k = 0; k < D; k++){
    float w1a = W1[k*D + lane],      w1b = W1[k*D + 64 + lane];
    float w2a = W2[k*D + lane],      w2b = W2[k*D + 64 + lane];
    #pragma unroll
    for (int r = 0; r < 16; r++){
      float2 sp = SP[wr0 + r][k];
      acc0[r] = fmaf(sp.x, w1a, fmaf(sp.y, w2a, acc0[r]));
      acc1[r] = fmaf(sp.x, w1b, fmaf(sp.y, w2b, acc1[r]));
    }
  }
  float bb0 = b1[lane]      + b2[lane];
  float bb1 = b1[64 + lane] + b2[64 + lane];
  #pragma unroll
  for (int r = 0; r < 16; r++){
    int row = row0 + wr0 + r;
    if (row < n){
      float v0 = acc0[r] + bb0; v0 = v0 > 0.f ? v0 : NEG_SLOPE*v0;
      float v1 = acc1[r] + bb1; v1 = v1 > 0.f ? v1 : NEG_SLOPE*v1;
      ego[(size_t)row*D + lane]      = v0;
      ego[(size_t)row*D + 64 + lane] = v1;
    }
  }
}

// Accumulate per-sample dot contributions of the current block (normalize=1 for layer outputs).
__global__ __launch_bounds__(256) void score_kernel(const float* __restrict__ base, const int* __restrict__ user,
                                                    const int* __restrict__ pos, const int* __restrict__ neg,
                                                    float* __restrict__ pacc, float* __restrict__ nacc,
                                                    int B, int U, int normalize){
  int w = (blockIdx.x*256 + threadIdx.x) >> 6;
  int lane = threadIdx.x & 63;
  if (w >= B) return;
  const float2* bp = (const float2*)base;
  size_t ur = (size_t)user[w] * 64;
  size_t pr = ((size_t)U + pos[w]) * 64;
  size_t nr = ((size_t)U + neg[w]) * 64;
  float2 uv = bp[ur + lane], pv = bp[pr + lane], nv = bp[nr + lane];
  float dup = uv.x*pv.x + uv.y*pv.y;
  float dun = uv.x*nv.x + uv.y*nv.y;
  float nu  = uv.x*uv.x + uv.y*uv.y;
  float np  = pv.x*pv.x + pv.y*pv.y;
  float nn  = nv.x*nv.x + nv.y*nv.y;
  dup = wave_red(dup); dun = wave_red(dun);
  nu = wave_red(nu); np = wave_red(np); nn = wave_red(nn);
  if (lane == 0){
    if (normalize){
      float inu = 1.f / fmaxf(sqrtf(nu), NORM_EPS);
      float inp = 1.f / fmaxf(sqrtf(np), NORM_EPS);
      float inn = 1.f / fmaxf(sqrtf(nn), NORM_EPS);
      pacc[w] += dup * inu * inp;
      nacc[w] += dun * inu * inn;
    } else {
      pacc[w] += dup;
      nacc[w] += dun;
    }
  }
}

__global__ __launch_bounds__(256) void reg_kernel(const float* __restrict__ item, const int* __restrict__ pos,
                                                  const int* __restrict__ neg, float* __restrict__ reg_out, int B){
  int w = (blockIdx.x*256 + threadIdx.x) >> 6;
  int lane = threadIdx.x & 63;
  if (w >= B) return;
  const float2* it = (const float2*)item;
  float2 pv = it[(size_t)pos[w]*64 + lane];
  float2 nv = it[(size_t)neg[w]*64 + lane];
  float v = pv.x*pv.x + pv.y*pv.y + nv.x*nv.x + nv.y*nv.y;
  v = wave_red(v);
  if (lane == 0) atomicAdd(reg_out, v);
}

__global__ __launch_bounds__(256) void final_kernel(const float* __restrict__ pacc, const float* __restrict__ nacc,
                                                    const float* __restrict__ reg_sum, float* __restrict__ out, int B){
  __shared__ float red[256];
  float s = 0.f;
  for (int i = threadIdx.x; i < B; i += 256){
    float x = nacc[i] - pacc[i];
    s += (x > 0.f) ? x + log1pf(expf(-x)) : log1pf(expf(x));   // softplus, stable
  }
  red[threadIdx.x] = s; __syncthreads();
  for (int o = 128; o > 0; o >>= 1){
    if (threadIdx.x < o) red[threadIdx.x] += red[threadIdx.x + o];
    __syncthreads();
  }
  if (threadIdx.x == 0){
    out[0] = red[0] / (float)B;
    out[1] = REG_LAMBDA * 0.5f * reg_sum[0] / (float)B;
  }
}

extern "C" void kernel_launch(void* const* d_in, const int* in_sizes, int n_in,
                              void* d_out, int out_size, void* d_ws, size_t ws_size,
                              hipStream_t stream) {
  const int*   user = (const int*)d_in[0];
  const int*   pos  = (const int*)d_in[1];
  const int*   neg  = (const int*)d_in[2];
  const int*   erow = (const int*)d_in[3];
  const int*   ecol = (const int*)d_in[4];
  const float* eval = (const float*)d_in[5];
  const float* uemb = (const float*)d_in[6];
  const float* iemb = (const float*)d_in[7];
  const float* Wg   = (const float*)d_in[8];
  const float* bg   = (const float*)d_in[9];
  const float* Wb   = (const float*)d_in[10];
  const float* bb   = (const float*)d_in[11];

  int B   = in_sizes[0];
  int NNZ = in_sizes[3];
  int U   = in_sizes[6] / D;
  int I   = in_sizes[7] / D;
  int N   = U + I;
  int L   = in_sizes[9] / D;

  char* wsp = (char*)d_ws;
  auto alloc = [&](size_t bytes) -> char* {
    char* p = wsp; wsp += (bytes + 255) & ~(size_t)255; return p;
  };
  float* ego    = (float*)alloc((size_t)N * D * 4);
  float* side   = (float*)alloc((size_t)N * D * 4);
  int*   scol   = (int*)  alloc((size_t)NNZ * 4);
  float* sval   = (float*)alloc((size_t)NNZ * 4);
  int*   rowptr = (int*)  alloc((size_t)(N + 1) * 4);
  int*   cursor = (int*)  alloc((size_t)N * 4);
  int*   counts = (int*)  alloc((size_t)N * 4);
  int*   bsums  = (int*)  alloc(1024 * 4);
  float* pacc   = (float*)alloc((size_t)B * 4);
  float* nacc   = (float*)alloc((size_t)B * 4);
  float* regs   = (float*)alloc(256);

  hipMemsetAsync(counts, 0, (size_t)N * 4, stream);
  hipMemsetAsync(pacc, 0, (size_t)B * 4, stream);
  hipMemsetAsync(nacc, 0, (size_t)B * 4, stream);
  hipMemsetAsync(regs, 0, 4, stream);
  hipMemcpyAsync(ego, uemb, (size_t)U * D * 4, hipMemcpyDeviceToDevice, stream);
  hipMemcpyAsync(ego + (size_t)U * D, iemb, (size_t)I * D * 4, hipMemcpyDeviceToDevice, stream);

  // CSR build
  hist_kernel<<<(NNZ + 255) / 256, 256, 0, stream>>>(erow, counts, NNZ);
  int nb = (N + 1023) / 1024;
  scan1_kernel<<<nb, 1024, 0, stream>>>(counts, rowptr, bsums, N);
  scan2_kernel<<<1, 1024, 0, stream>>>(bsums, nb);
  scan3_kernel<<<nb, 1024, 0, stream>>>(rowptr, bsums, N, NNZ);
  hipMemcpyAsync(cursor, rowptr, (size_t)N * 4, hipMemcpyDeviceToDevice, stream);
  scatter_kernel<<<(NNZ + 255) / 256, 256, 0, stream>>>(erow, ecol, eval, cursor, scol, sval, NNZ);

  // Block 0 (raw embeddings, un-normalized)
  score_kernel<<<(B + 3) / 4, 256, 0, stream>>>(ego, user, pos, neg, pacc, nacc, B, U, 0);

  for (int l = 0; l < L; l++){
    spmm_kernel<<<(N + 3) / 4, 256, 0, stream>>>(rowptr, scol, sval, ego, side, N);
    transform_kernel<<<(N + TROWS - 1) / TROWS, 256, 0, stream>>>(
        side, ego, Wg + (size_t)l * D * D, Wb + (size_t)l * D * D,
        bg + (size_t)l * D, bb + (size_t)l * D, N);
    score_kernel<<<(B + 3) / 4, 256, 0, stream>>>(ego, user, pos, neg, pacc, nacc, B, U, 1);
  }

  reg_kernel<<<(B + 3) / 4, 256, 0, stream>>>(iemb, pos, neg, regs, B);
  final_kernel<<<1, 256, 0, stream>>>(pacc, nacc, regs, (float*)d_out, B);
}

// Round 2
// 2087.502 us; speedup vs baseline: 1.1583x; 1.1583x over previous
//
#include <hip/hip_runtime.h>
#include <math.h>

#define D 128
#define TROWS 64
#define NEG_SLOPE 0.2f
#define REG_LAMBDA 1e-4f
#define NORM_EPS 1e-12f

__device__ __forceinline__ float wave_red(float v){
  #pragma unroll
  for (int o = 32; o > 0; o >>= 1) v += __shfl_xor(v, o, 64);
  return v;
}

__device__ __forceinline__ unsigned short f2bf(float f){
  unsigned int u = __float_as_uint(f);
  unsigned int r = (u + 0x7fffu + ((u >> 16) & 1u)) >> 16;  // RNE
  return (unsigned short)r;
}
__device__ __forceinline__ float bf_lo(unsigned int x){ return __uint_as_float(x << 16); }
__device__ __forceinline__ float bf_hi(unsigned int x){ return __uint_as_float(x & 0xffff0000u); }

__global__ __launch_bounds__(256) void hist_kernel(const int* __restrict__ erow, int* __restrict__ counts, int nnz){
  int e = blockIdx.x*256 + threadIdx.x;
  if (e < nnz) atomicAdd(&counts[erow[e]], 1);
}

__global__ __launch_bounds__(1024) void scan1_kernel(const int* __restrict__ counts, int* __restrict__ rowptr, int* __restrict__ sums, int n){
  __shared__ int tmp[1024];
  int t = threadIdx.x; int i = blockIdx.x*1024 + t;
  int v = (i < n) ? counts[i] : 0;
  tmp[t] = v; __syncthreads();
  #pragma unroll
  for (int off = 1; off < 1024; off <<= 1){
    int a = (t >= off) ? tmp[t-off] : 0; __syncthreads();
    tmp[t] += a; __syncthreads();
  }
  if (i < n) rowptr[i] = tmp[t] - v;   // exclusive within block
  if (t == 1023) sums[blockIdx.x] = tmp[t];
}

__global__ __launch_bounds__(1024) void scan2_kernel(int* __restrict__ sums, int nb){
  __shared__ int tmp[1024];
  int t = threadIdx.x;
  int v = (t < nb) ? sums[t] : 0;
  tmp[t] = v; __syncthreads();
  #pragma unroll
  for (int off = 1; off < 1024; off <<= 1){
    int a = (t >= off) ? tmp[t-off] : 0; __syncthreads();
    tmp[t] += a; __syncthreads();
  }
  if (t < nb) sums[t] = tmp[t] - v;    // exclusive block offsets
}

__global__ __launch_bounds__(1024) void scan3_kernel(int* __restrict__ rowptr, const int* __restrict__ sums, int n, int nnz){
  int i = blockIdx.x*1024 + threadIdx.x;
  if (i < n) rowptr[i] += sums[blockIdx.x];
  if (i == 0) rowptr[n] = nnz;
}

// Pack (col, val) into one int2 -> single 8B random write (half the line footprint).
__global__ __launch_bounds__(256) void scatter_kernel(const int* __restrict__ erow, const int* __restrict__ ecol,
                                                      const float* __restrict__ eval, int* __restrict__ cursor,
                                                      int2* __restrict__ ep, int nnz){
  int e = blockIdx.x*256 + threadIdx.x;
  if (e >= nnz) return;
  int r = erow[e];
  int p = atomicAdd(&cursor[r], 1);
  int2 v; v.x = ecol[e]; v.y = __float_as_int(eval[e]);
  ep[p] = v;
}

// float2 pairs -> packed bf16 (2 per uint)
__global__ __launch_bounds__(256) void tobf16_kernel(const float* __restrict__ src, unsigned int* __restrict__ dst, int npairs){
  int i = blockIdx.x*256 + threadIdx.x;
  if (i >= npairs) return;
  float2 v = ((const float2*)src)[i];
  dst[i] = (unsigned int)f2bf(v.x) | ((unsigned int)f2bf(v.y) << 16);
}

// side[r] = sum_e val_e * ego_bf16[col_e] ; one wave per row, 2 bf16 elems/lane, fp32 accum.
__global__ __launch_bounds__(256) void spmm_kernel(const int* __restrict__ rowptr, const int2* __restrict__ ep,
                                                   const unsigned int* __restrict__ egob,
                                                   float* __restrict__ side, int n){
  int w = (blockIdx.x*256 + threadIdx.x) >> 6;
  int lane = threadIdx.x & 63;
  if (w >= n) return;
  int s = rowptr[w], e = rowptr[w+1];
  float ax = 0.f, ay = 0.f;
  int i = s;
  for (; i + 3 < e; i += 4){
    int2 e0 = ep[i], e1 = ep[i+1], e2 = ep[i+2], e3 = ep[i+3];
    unsigned int x0 = egob[(size_t)e0.x*64 + lane];
    unsigned int x1 = egob[(size_t)e1.x*64 + lane];
    unsigned int x2 = egob[(size_t)e2.x*64 + lane];
    unsigned int x3 = egob[(size_t)e3.x*64 + lane];
    float v0 = __int_as_float(e0.y), v1 = __int_as_float(e1.y);
    float v2 = __int_as_float(e2.y), v3 = __int_as_float(e3.y);
    ax = fmaf(v0, bf_lo(x0), ax); ay = fmaf(v0, bf_hi(x0), ay);
    ax = fmaf(v1, bf_lo(x1), ax); ay = fmaf(v1, bf_hi(x1), ay);
    ax = fmaf(v2, bf_lo(x2), ax); ay = fmaf(v2, bf_hi(x2), ay);
    ax = fmaf(v3, bf_lo(x3), ax); ay = fmaf(v3, bf_hi(x3), ay);
  }
  for (; i < e; i++){
    int2 e0 = ep[i];
    unsigned int x0 = egob[(size_t)e0.x*64 + lane];
    float v0 = __int_as_float(e0.y);
    ax = fmaf(v0, bf_lo(x0), ax); ay = fmaf(v0, bf_hi(x0), ay);
  }
  ((float2*)side)[(size_t)w*64 + lane] = make_float2(ax, ay);
}

// ego[r] = leaky( side[r]@W1 + (ego[r].*side[r])@W2 + b1 + b2 ), in place; also writes bf16 shadow.
__global__ __launch_bounds__(256) void transform_kernel(const float* __restrict__ side, float* __restrict__ ego,
                                                        unsigned short* __restrict__ egob,
                                                        const float* __restrict__ W1, const float* __restrict__ W2,
                                                        const float* __restrict__ b1, const float* __restrict__ b2, int n){
  __shared__ float2 SP[TROWS][D];   // 64 KiB: (s, s*e) per element
  int row0 = blockIdx.x * TROWS;
  for (int idx = threadIdx.x; idx < TROWS*D; idx += 256){
    int r = idx >> 7, c = idx & 127;
    int row = row0 + r;
    float s = 0.f, p = 0.f;
    if (row < n){
      s = side[(size_t)row*D + c];
      p = s * ego[(size_t)row*D + c];
    }
    SP[r][c] = make_float2(s, p);
  }
  __syncthreads();
  int wave = threadIdx.x >> 6, lane = threadIdx.x & 63;
  int wr0 = wave * 16;
  float acc0[16], acc1[16];
  #pragma unroll
  for (int r = 0; r < 16; r++){ acc0[r] = 0.f; acc1[r] = 0.f; }
  #pragma unroll 2
  for (int k = 0; k < D; k++){
    float w1a = W1[k*D + lane],      w1b = W1[k*D + 64 + lane];
    float w2a = W2[k*D + lane],      w2b = W2[k*D + 64 + lane];
    #pragma unroll
    for (int r = 0; r < 16; r++){
      float2 sp = SP[wr0 + r][k];
      acc0[r] = fmaf(sp.x, w1a, fmaf(sp.y, w2a, acc0[r]));
      acc1[r] = fmaf(sp.x, w1b, fmaf(sp.y, w2b, acc1[r]));
    }
  }
  float bb0 = b1[lane]      + b2[lane];
  float bb1 = b1[64 + lane] + b2[64 + lane];
  #pragma unroll
  for (int r = 0; r < 16; r++){
    int row = row0 + wr0 + r;
    if (row < n){
      float v0 = acc0[r] + bb0; v0 = v0 > 0.f ? v0 : NEG_SLOPE*v0;
      float v1 = acc1[r] + bb1; v1 = v1 > 0.f ? v1 : NEG_SLOPE*v1;
      ego[(size_t)row*D + lane]      = v0;
      ego[(size_t)row*D + 64 + lane] = v1;
      egob[(size_t)row*D + lane]      = f2bf(v0);
      egob[(size_t)row*D + 64 + lane] = f2bf(v1);
    }
  }
}

// Accumulate per-sample dot contributions of the current block (normalize=1 for layer outputs).
__global__ __launch_bounds__(256) void score_kernel(const float* __restrict__ base, const int* __restrict__ user,
                                                    const int* __restrict__ pos, const int* __restrict__ neg,
                                                    float* __restrict__ pacc, float* __restrict__ nacc,
                                                    int B, int U, int normalize){
  int w = (blockIdx.x*256 + threadIdx.x) >> 6;
  int lane = threadIdx.x & 63;
  if (w >= B) return;
  const float2* bp = (const float2*)base;
  size_t ur = (size_t)user[w] * 64;
  size_t pr = ((size_t)U + pos[w]) * 64;
  size_t nr = ((size_t)U + neg[w]) * 64;
  float2 uv = bp[ur + lane], pv = bp[pr + lane], nv = bp[nr + lane];
  float dup = uv.x*pv.x + uv.y*pv.y;
  float dun = uv.x*nv.x + uv.y*nv.y;
  float nu  = uv.x*uv.x + uv.y*uv.y;
  float np  = pv.x*pv.x + pv.y*pv.y;
  float nn  = nv.x*nv.x + nv.y*nv.y;
  dup = wave_red(dup); dun = wave_red(dun);
  nu = wave_red(nu); np = wave_red(np); nn = wave_red(nn);
  if (lane == 0){
    if (normalize){
      float inu = 1.f / fmaxf(sqrtf(nu), NORM_EPS);
      float inp = 1.f / fmaxf(sqrtf(np), NORM_EPS);
      float inn = 1.f / fmaxf(sqrtf(nn), NORM_EPS);
      pacc[w] += dup * inu * inp;
      nacc[w] += dun * inu * inn;
    } else {
      pacc[w] += dup;
      nacc[w] += dun;
    }
  }
}

__global__ __launch_bounds__(256) void reg_kernel(const float* __restrict__ item, const int* __restrict__ pos,
                                                  const int* __restrict__ neg, float* __restrict__ reg_out, int B){
  int w = (blockIdx.x*256 + threadIdx.x) >> 6;
  int lane = threadIdx.x & 63;
  if (w >= B) return;
  const float2* it = (const float2*)item;
  float2 pv = it[(size_t)pos[w]*64 + lane];
  float2 nv = it[(size_t)neg[w]*64 + lane];
  float v = pv.x*pv.x + pv.y*pv.y + nv.x*nv.x + nv.y*nv.y;
  v = wave_red(v);
  if (lane == 0) atomicAdd(reg_out, v);
}

__global__ __launch_bounds__(256) void final_kernel(const float* __restrict__ pacc, const float* __restrict__ nacc,
                                                    const float* __restrict__ reg_sum, float* __restrict__ out, int B){
  __shared__ float red[256];
  float s = 0.f;
  for (int i = threadIdx.x; i < B; i += 256){
    float x = nacc[i] - pacc[i];
    s += (x > 0.f) ? x + log1pf(expf(-x)) : log1pf(expf(x));   // softplus, stable
  }
  red[threadIdx.x] = s; __syncthreads();
  for (int o = 128; o > 0; o >>= 1){
    if (threadIdx.x < o) red[threadIdx.x] += red[threadIdx.x + o];
    __syncthreads();
  }
  if (threadIdx.x == 0){
    out[0] = red[0] / (float)B;
    out[1] = REG_LAMBDA * 0.5f * reg_sum[0] / (float)B;
  }
}

extern "C" void kernel_launch(void* const* d_in, const int* in_sizes, int n_in,
                              void* d_out, int out_size, void* d_ws, size_t ws_size,
                              hipStream_t stream) {
  const int*   user = (const int*)d_in[0];
  const int*   pos  = (const int*)d_in[1];
  const int*   neg  = (const int*)d_in[2];
  const int*   erow = (const int*)d_in[3];
  const int*   ecol = (const int*)d_in[4];
  const float* eval = (const float*)d_in[5];
  const float* uemb = (const float*)d_in[6];
  const float* iemb = (const float*)d_in[7];
  const float* Wg   = (const float*)d_in[8];
  const float* bg   = (const float*)d_in[9];
  const float* Wb   = (const float*)d_in[10];
  const float* bb   = (const float*)d_in[11];

  int B   = in_sizes[0];
  int NNZ = in_sizes[3];
  int U   = in_sizes[6] / D;
  int I   = in_sizes[7] / D;
  int N   = U + I;
  int L   = in_sizes[9] / D;

  char* wsp = (char*)d_ws;
  auto alloc = [&](size_t bytes) -> char* {
    char* p = wsp; wsp += (bytes + 255) & ~(size_t)255; return p;
  };
  float*         ego    = (float*)alloc((size_t)N * D * 4);
  float*         side   = (float*)alloc((size_t)N * D * 4);
  unsigned int*  egob   = (unsigned int*)alloc((size_t)N * D * 2);  // bf16 shadow (packed 2/uint)
  int2*          ep     = (int2*) alloc((size_t)NNZ * 8);
  int*           rowptr = (int*)  alloc((size_t)(N + 1) * 4);
  int*           cursor = (int*)  alloc((size_t)N * 4);
  int*           counts = (int*)  alloc((size_t)N * 4);
  int*           bsums  = (int*)  alloc(1024 * 4);
  float*         pacc   = (float*)alloc((size_t)B * 4);
  float*         nacc   = (float*)alloc((size_t)B * 4);
  float*         regs   = (float*)alloc(256);

  hipMemsetAsync(counts, 0, (size_t)N * 4, stream);
  hipMemsetAsync(pacc, 0, (size_t)B * 4, stream);
  hipMemsetAsync(nacc, 0, (size_t)B * 4, stream);
  hipMemsetAsync(regs, 0, 4, stream);
  hipMemcpyAsync(ego, uemb, (size_t)U * D * 4, hipMemcpyDeviceToDevice, stream);
  hipMemcpyAsync(ego + (size_t)U * D, iemb, (size_t)I * D * 4, hipMemcpyDeviceToDevice, stream);

  // bf16 shadow of initial ego
  int npairs = N * (D/2);
  tobf16_kernel<<<(npairs + 255) / 256, 256, 0, stream>>>(ego, egob, npairs);

  // CSR build
  hist_kernel<<<(NNZ + 255) / 256, 256, 0, stream>>>(erow, counts, NNZ);
  int nb = (N + 1023) / 1024;
  scan1_kernel<<<nb, 1024, 0, stream>>>(counts, rowptr, bsums, N);
  scan2_kernel<<<1, 1024, 0, stream>>>(bsums, nb);
  scan3_kernel<<<nb, 1024, 0, stream>>>(rowptr, bsums, N, NNZ);
  hipMemcpyAsync(cursor, rowptr, (size_t)N * 4, hipMemcpyDeviceToDevice, stream);
  scatter_kernel<<<(NNZ + 255) / 256, 256, 0, stream>>>(erow, ecol, eval, cursor, ep, NNZ);

  // Block 0 (raw embeddings, un-normalized)
  score_kernel<<<(B + 3) / 4, 256, 0, stream>>>(ego, user, pos, neg, pacc, nacc, B, U, 0);

  for (int l = 0; l < L; l++){
    spmm_kernel<<<(N + 3) / 4, 256, 0, stream>>>(rowptr, ep, egob, side, N);
    transform_kernel<<<(N + TROWS - 1) / TROWS, 256, 0, stream>>>(
        side, ego, (unsigned short*)egob,
        Wg + (size_t)l * D * D, Wb + (size_t)l * D * D,
        bg + (size_t)l * D, bb + (size_t)l * D, N);
    score_kernel<<<(B + 3) / 4, 256, 0, stream>>>(ego, user, pos, neg, pacc, nacc, B, U, 1);
  }

  reg_kernel<<<(B + 3) / 4, 256, 0, stream>>>(iemb, pos, neg, regs, B);
  final_kernel<<<1, 256, 0, stream>>>(pacc, nacc, regs, (float*)d_out, B);
}

// Round 3
// 1562.696 us; speedup vs baseline: 1.5473x; 1.3358x over previous
//
#include <hip/hip_runtime.h>
#include <math.h>

#define D 128
#define TROWS 64
#define NEG_SLOPE 0.2f
#define REG_LAMBDA 1e-4f
#define NORM_EPS 1e-12f

#define RPB 256          // rows per coarse bucket
#define RPB_SHIFT 8
#define MAXB 1024        // max buckets supported (N <= 262144)
#define CHUNK 4096       // edges per bscatter block

__device__ __forceinline__ float wave_red(float v){
  #pragma unroll
  for (int o = 32; o > 0; o >>= 1) v += __shfl_xor(v, o, 64);
  return v;
}

__device__ __forceinline__ unsigned short f2bf(float f){
  unsigned int u = __float_as_uint(f);
  unsigned int r = (u + 0x7fffu + ((u >> 16) & 1u)) >> 16;  // RNE
  return (unsigned short)r;
}
__device__ __forceinline__ float bf_lo(unsigned int x){ return __uint_as_float(x << 16); }
__device__ __forceinline__ float bf_hi(unsigned int x){ return __uint_as_float(x & 0xffff0000u); }

// float2 pairs -> packed bf16 (2 per uint)
__global__ __launch_bounds__(256) void tobf16_kernel(const float* __restrict__ src, unsigned int* __restrict__ dst, int npairs){
  int i = blockIdx.x*256 + threadIdx.x;
  if (i >= npairs) return;
  float2 v = ((const float2*)src)[i];
  dst[i] = (unsigned int)f2bf(v.x) | ((unsigned int)f2bf(v.y) << 16);
}

// K1: coarse bucket histogram, LDS-aggregated
__global__ __launch_bounds__(256) void bhist_kernel(const int* __restrict__ erow, int* __restrict__ bcnt, int nnz, int nbk){
  __shared__ int h[MAXB];
  for (int i = threadIdx.x; i < nbk; i += 256) h[i] = 0;
  __syncthreads();
  int stride = gridDim.x * 256;
  for (int e = blockIdx.x*256 + threadIdx.x; e < nnz; e += stride)
    atomicAdd(&h[erow[e] >> RPB_SHIFT], 1);
  __syncthreads();
  for (int i = threadIdx.x; i < nbk; i += 256){
    int c = h[i];
    if (c) atomicAdd(&bcnt[i], c);
  }
}

// K2: exclusive scan of bucket counts (single block)
__global__ __launch_bounds__(1024) void bscan_kernel(const int* __restrict__ bcnt, int* __restrict__ bbase,
                                                     int* __restrict__ bcur, int* __restrict__ rowptr,
                                                     int nbk, int nnz, int n){
  __shared__ int tmp[1024];
  int t = threadIdx.x;
  int v = (t < nbk) ? bcnt[t] : 0;
  tmp[t] = v; __syncthreads();
  #pragma unroll
  for (int off = 1; off < 1024; off <<= 1){
    int a = (t >= off) ? tmp[t-off] : 0; __syncthreads();
    tmp[t] += a; __syncthreads();
  }
  if (t < nbk){ int b = tmp[t] - v; bbase[t] = b; bcur[t] = b; }
  if (t == 0){ bbase[nbk] = nnz; rowptr[n] = nnz; }
}

// K3: coarse scatter. Block sorts a CHUNK of edges by bucket in LDS, reserves
// global ranges (one atomic per bucket per block), writes coalesced runs.
// ebuf entry: x = col | (row_low8 << 20), y = val bits.
__global__ __launch_bounds__(256) void bscatter_kernel(const int* __restrict__ erow, const int* __restrict__ ecol,
                                                       const float* __restrict__ eval, int* __restrict__ bcur,
                                                       int2* __restrict__ ebuf, int nnz, int nbk){
  __shared__ int2 ls[CHUNK];     // 32 KB staged edges (bucket-sorted)
  __shared__ int gdst[CHUNK];    // 16 KB global destination per slot
  __shared__ int h[MAXB];        // counts, then adj = gbase - hx0
  __shared__ int hx[MAXB];       // exclusive scan, then running cursor
  __shared__ int tmp[256];
  int tid = threadIdx.x;
  int base = blockIdx.x * CHUNK;
  int cn = min(CHUNK, nnz - base);
  for (int i = tid; i < nbk; i += 256) h[i] = 0;
  __syncthreads();
  for (int i = tid; i < cn; i += 256)
    atomicAdd(&h[erow[base+i] >> RPB_SHIFT], 1);
  __syncthreads();
  // exclusive scan h[0..nbk) -> hx, 4 buckets per thread
  int b0 = tid*4;
  int c0=0,c1=0,c2=0,c3=0;
  if (b0 < nbk){
    c0 = h[b0];
    if (b0+1 < nbk) c1 = h[b0+1];
    if (b0+2 < nbk) c2 = h[b0+2];
    if (b0+3 < nbk) c3 = h[b0+3];
  }
  int tsum = c0+c1+c2+c3;
  tmp[tid] = tsum; __syncthreads();
  #pragma unroll
  for (int off = 1; off < 256; off <<= 1){
    int a = (tid >= off) ? tmp[tid-off] : 0; __syncthreads();
    tmp[tid] += a; __syncthreads();
  }
  int tbase = tmp[tid] - tsum;
  if (b0 < nbk){
    hx[b0] = tbase;
    if (b0+1 < nbk) hx[b0+1] = tbase + c0;
    if (b0+2 < nbk) hx[b0+2] = tbase + c0 + c1;
    if (b0+3 < nbk) hx[b0+3] = tbase + c0 + c1 + c2;
  }
  __syncthreads();
  // reserve global ranges; h becomes adj so gdst = h[b] + lpos
  for (int i = tid; i < nbk; i += 256){
    int c = h[i];
    if (c > 0){
      int gb = atomicAdd(&bcur[i], c);
      h[i] = gb - hx[i];
    }
  }
  __syncthreads();
  // stage bucket-sorted
  for (int i = tid; i < cn; i += 256){
    int r = erow[base+i];
    int b = r >> RPB_SHIFT;
    int x = ecol[base+i] | ((r & (RPB-1)) << 20);
    int lpos = atomicAdd(&hx[b], 1);
    ls[lpos] = make_int2(x, __float_as_int(eval[base+i]));
    gdst[lpos] = h[b] + lpos;
  }
  __syncthreads();
  for (int i = tid; i < cn; i += 256)
    ebuf[gdst[i]] = ls[i];
}

// K4: one block per bucket. LDS row-hist + scan -> rowptr; fine scatter into
// final CSR slots (destination region ~64 KB, L2-local full-line writes).
__global__ __launch_bounds__(256) void fscatter_kernel(const int2* __restrict__ ebuf, const int* __restrict__ bbase,
                                                       int2* __restrict__ ep, int* __restrict__ rowptr, int n){
  __shared__ int rh[RPB];
  __shared__ int rx[RPB];
  int b = blockIdx.x;
  int tid = threadIdx.x;
  int s = bbase[b], e = bbase[b+1];
  int row0 = b << RPB_SHIFT;
  rh[tid] = 0;
  __syncthreads();
  for (int i = s + tid; i < e; i += 256)
    atomicAdd(&rh[ebuf[i].x >> 20], 1);
  __syncthreads();
  int v = rh[tid];
  rx[tid] = v; __syncthreads();
  #pragma unroll
  for (int off = 1; off < 256; off <<= 1){
    int a = (tid >= off) ? rx[tid-off] : 0; __syncthreads();
    rx[tid] += a; __syncthreads();
  }
  int excl = rx[tid] - v;
  __syncthreads();
  if (row0 + tid < n) rowptr[row0 + tid] = s + excl;
  rh[tid] = s + excl;   // reuse as global cursor
  __syncthreads();
  for (int i = s + tid; i < e; i += 256){
    int2 x = ebuf[i];
    int rl = x.x >> 20;
    int p = atomicAdd(&rh[rl], 1);
    ep[p] = make_int2(x.x & 0xFFFFF, x.y);
  }
}

// side[r] = sum_e val_e * ego_bf16[col_e] ; one wave per row, fp32 accum.
__global__ __launch_bounds__(256) void spmm_kernel(const int* __restrict__ rowptr, const int2* __restrict__ ep,
                                                   const unsigned int* __restrict__ egob,
                                                   float* __restrict__ side, int n){
  int w = (blockIdx.x*256 + threadIdx.x) >> 6;
  int lane = threadIdx.x & 63;
  if (w >= n) return;
  int s = rowptr[w], e = rowptr[w+1];
  float ax = 0.f, ay = 0.f;
  int i = s;
  for (; i + 3 < e; i += 4){
    int2 e0 = ep[i], e1 = ep[i+1], e2 = ep[i+2], e3 = ep[i+3];
    unsigned int x0 = egob[(size_t)e0.x*64 + lane];
    unsigned int x1 = egob[(size_t)e1.x*64 + lane];
    unsigned int x2 = egob[(size_t)e2.x*64 + lane];
    unsigned int x3 = egob[(size_t)e3.x*64 + lane];
    float v0 = __int_as_float(e0.y), v1 = __int_as_float(e1.y);
    float v2 = __int_as_float(e2.y), v3 = __int_as_float(e3.y);
    ax = fmaf(v0, bf_lo(x0), ax); ay = fmaf(v0, bf_hi(x0), ay);
    ax = fmaf(v1, bf_lo(x1), ax); ay = fmaf(v1, bf_hi(x1), ay);
    ax = fmaf(v2, bf_lo(x2), ax); ay = fmaf(v2, bf_hi(x2), ay);
    ax = fmaf(v3, bf_lo(x3), ax); ay = fmaf(v3, bf_hi(x3), ay);
  }
  for (; i < e; i++){
    int2 e0 = ep[i];
    unsigned int x0 = egob[(size_t)e0.x*64 + lane];
    float v0 = __int_as_float(e0.y);
    ax = fmaf(v0, bf_lo(x0), ax); ay = fmaf(v0, bf_hi(x0), ay);
  }
  ((float2*)side)[(size_t)w*64 + lane] = make_float2(ax, ay);
}

// egob[r] = bf16( leaky( side[r]@W1 + (ego[r].*side[r])@W2 + b1 + b2 ) ).
// Lane owns columns (2*lane, 2*lane+1) -> pair-packed bf16 output.
__global__ __launch_bounds__(256) void transform_kernel(const float* __restrict__ side, unsigned int* __restrict__ egob,
                                                        const float* __restrict__ W1, const float* __restrict__ W2,
                                                        const float* __restrict__ b1, const float* __restrict__ b2, int n){
  __shared__ float2 SP[TROWS][D];   // 64 KiB: (s, s*e) per element
  int row0 = blockIdx.x * TROWS;
  for (int idx = threadIdx.x; idx < TROWS*64; idx += 256){
    int r = idx >> 6, cp = idx & 63;
    int row = row0 + r;
    float2 sp0 = make_float2(0.f, 0.f), sp1 = make_float2(0.f, 0.f);
    if (row < n){
      float2 s2 = ((const float2*)side)[(size_t)row*64 + cp];
      unsigned int eb = egob[(size_t)row*64 + cp];
      sp0 = make_float2(s2.x, s2.x * bf_lo(eb));
      sp1 = make_float2(s2.y, s2.y * bf_hi(eb));
    }
    SP[r][2*cp]   = sp0;
    SP[r][2*cp+1] = sp1;
  }
  __syncthreads();
  int wave = threadIdx.x >> 6, lane = threadIdx.x & 63;
  int wr0 = wave * 16;
  float acc0[16], acc1[16];
  #pragma unroll
  for (int r = 0; r < 16; r++){ acc0[r] = 0.f; acc1[r] = 0.f; }
  #pragma unroll 2
  for (int k = 0; k < D; k++){
    float2 w1 = ((const float2*)(W1 + (size_t)k*D))[lane];   // cols 2lane, 2lane+1
    float2 w2 = ((const float2*)(W2 + (size_t)k*D))[lane];
    #pragma unroll
    for (int r = 0; r < 16; r++){
      float2 sp = SP[wr0 + r][k];
      acc0[r] = fmaf(sp.x, w1.x, fmaf(sp.y, w2.x, acc0[r]));
      acc1[r] = fmaf(sp.x, w1.y, fmaf(sp.y, w2.y, acc1[r]));
    }
  }
  float2 bv1 = ((const float2*)b1)[lane];
  float2 bv2 = ((const float2*)b2)[lane];
  float bb0 = bv1.x + bv2.x, bb1 = bv1.y + bv2.y;
  #pragma unroll
  for (int r = 0; r < 16; r++){
    int row = row0 + wr0 + r;
    if (row < n){
      float v0 = acc0[r] + bb0; v0 = v0 > 0.f ? v0 : NEG_SLOPE*v0;
      float v1 = acc1[r] + bb1; v1 = v1 > 0.f ? v1 : NEG_SLOPE*v1;
      egob[(size_t)row*64 + lane] = (unsigned int)f2bf(v0) | ((unsigned int)f2bf(v1) << 16);
    }
  }
}

// Accumulate per-sample dot contributions of the current block (bf16 base).
__global__ __launch_bounds__(256) void score_kernel(const unsigned int* __restrict__ egob, const int* __restrict__ user,
                                                    const int* __restrict__ pos, const int* __restrict__ neg,
                                                    float* __restrict__ pacc, float* __restrict__ nacc,
                                                    int B, int U, int normalize){
  int w = (blockIdx.x*256 + threadIdx.x) >> 6;
  int lane = threadIdx.x & 63;
  if (w >= B) return;
  size_t ur = (size_t)user[w] * 64;
  size_t pr = ((size_t)U + pos[w]) * 64;
  size_t nr = ((size_t)U + neg[w]) * 64;
  unsigned int ub = egob[ur + lane], pb = egob[pr + lane], nb = egob[nr + lane];
  float ux = bf_lo(ub), uy = bf_hi(ub);
  float px = bf_lo(pb), py = bf_hi(pb);
  float nx = bf_lo(nb), ny = bf_hi(nb);
  float dup = ux*px + uy*py;
  float dun = ux*nx + uy*ny;
  float nu  = ux*ux + uy*uy;
  float np  = px*px + py*py;
  float nn  = nx*nx + ny*ny;
  dup = wave_red(dup); dun = wave_red(dun);
  nu = wave_red(nu); np = wave_red(np); nn = wave_red(nn);
  if (lane == 0){
    if (normalize){
      float inu = 1.f / fmaxf(sqrtf(nu), NORM_EPS);
      float inp = 1.f / fmaxf(sqrtf(np), NORM_EPS);
      float inn = 1.f / fmaxf(sqrtf(nn), NORM_EPS);
      pacc[w] += dup * inu * inp;
      nacc[w] += dun * inu * inn;
    } else {
      pacc[w] += dup;
      nacc[w] += dun;
    }
  }
}

__global__ __launch_bounds__(256) void reg_kernel(const float* __restrict__ item, const int* __restrict__ pos,
                                                  const int* __restrict__ neg, float* __restrict__ reg_out, int B){
  int w = (blockIdx.x*256 + threadIdx.x) >> 6;
  int lane = threadIdx.x & 63;
  if (w >= B) return;
  const float2* it = (const float2*)item;
  float2 pv = it[(size_t)pos[w]*64 + lane];
  float2 nv = it[(size_t)neg[w]*64 + lane];
  float v = pv.x*pv.x + pv.y*pv.y + nv.x*nv.x + nv.y*nv.y;
  v = wave_red(v);
  if (lane == 0) atomicAdd(reg_out, v);
}

__global__ __launch_bounds__(256) void final_kernel(const float* __restrict__ pacc, const float* __restrict__ nacc,
                                                    const float* __restrict__ reg_sum, float* __restrict__ out, int B){
  __shared__ float red[256];
  float s = 0.f;
  for (int i = threadIdx.x; i < B; i += 256){
    float x = nacc[i] - pacc[i];
    s += (x > 0.f) ? x + log1pf(expf(-x)) : log1pf(expf(x));   // softplus, stable
  }
  red[threadIdx.x] = s; __syncthreads();
  for (int o = 128; o > 0; o >>= 1){
    if (threadIdx.x < o) red[threadIdx.x] += red[threadIdx.x + o];
    __syncthreads();
  }
  if (threadIdx.x == 0){
    out[0] = red[0] / (float)B;
    out[1] = REG_LAMBDA * 0.5f * reg_sum[0] / (float)B;
  }
}

extern "C" void kernel_launch(void* const* d_in, const int* in_sizes, int n_in,
                              void* d_out, int out_size, void* d_ws, size_t ws_size,
                              hipStream_t stream) {
  const int*   user = (const int*)d_in[0];
  const int*   pos  = (const int*)d_in[1];
  const int*   neg  = (const int*)d_in[2];
  const int*   erow = (const int*)d_in[3];
  const int*   ecol = (const int*)d_in[4];
  const float* eval = (const float*)d_in[5];
  const float* uemb = (const float*)d_in[6];
  const float* iemb = (const float*)d_in[7];
  const float* Wg   = (const float*)d_in[8];
  const float* bg   = (const float*)d_in[9];
  const float* Wb   = (const float*)d_in[10];
  const float* bb   = (const float*)d_in[11];

  int B   = in_sizes[0];
  int NNZ = in_sizes[3];
  int U   = in_sizes[6] / D;
  int I   = in_sizes[7] / D;
  int N   = U + I;
  int L   = in_sizes[9] / D;
  int nbk = (N + RPB - 1) >> RPB_SHIFT;

  char* wsp = (char*)d_ws;
  auto alloc = [&](size_t bytes) -> char* {
    char* p = wsp; wsp += (bytes + 255) & ~(size_t)255; return p;
  };
  float*         side   = (float*)alloc((size_t)N * D * 4);            // also aliased as ebuf during build
  unsigned int*  egob   = (unsigned int*)alloc((size_t)N * D * 2);     // bf16 ego, pair-packed
  int2*          ep     = (int2*) alloc((size_t)NNZ * 8);              // final CSR (col|rl<<20 cleared, val)
  int*           rowptr = (int*)  alloc((size_t)(N + 1) * 4);
  int*           bcnt   = (int*)  alloc((size_t)MAXB * 4);
  int*           bbase  = (int*)  alloc((size_t)(MAXB + 1) * 4);
  int*           bcur   = (int*)  alloc((size_t)MAXB * 4);
  float*         pacc   = (float*)alloc((size_t)B * 4);
  float*         nacc   = (float*)alloc((size_t)B * 4);
  float*         regs   = (float*)alloc(256);
  int2*          ebuf   = (int2*)side;   // staging: NNZ*8 <= N*D*4

  hipMemsetAsync(bcnt, 0, (size_t)nbk * 4, stream);
  hipMemsetAsync(pacc, 0, (size_t)B * 4, stream);
  hipMemsetAsync(nacc, 0, (size_t)B * 4, stream);
  hipMemsetAsync(regs, 0, 4, stream);

  // bf16 ego directly from input embeddings
  tobf16_kernel<<<(U*64 + 255) / 256, 256, 0, stream>>>(uemb, egob, U*64);
  tobf16_kernel<<<(I*64 + 255) / 256, 256, 0, stream>>>(iemb, egob + (size_t)U*64, I*64);

  // Bucketed CSR build
  bhist_kernel<<<2048, 256, 0, stream>>>(erow, bcnt, NNZ, nbk);
  bscan_kernel<<<1, 1024, 0, stream>>>(bcnt, bbase, bcur, rowptr, nbk, NNZ, N);
  bscatter_kernel<<<(NNZ + CHUNK - 1) / CHUNK, 256, 0, stream>>>(erow, ecol, eval, bcur, ebuf, NNZ, nbk);
  fscatter_kernel<<<nbk, 256, 0, stream>>>(ebuf, bbase, ep, rowptr, N);

  // Block 0 (raw embeddings, un-normalized)
  score_kernel<<<(B + 3) / 4, 256, 0, stream>>>(egob, user, pos, neg, pacc, nacc, B, U, 0);

  for (int l = 0; l < L; l++){
    spmm_kernel<<<(N + 3) / 4, 256, 0, stream>>>(rowptr, ep, egob, side, N);
    transform_kernel<<<(N + TROWS - 1) / TROWS, 256, 0, stream>>>(
        side, egob,
        Wg + (size_t)l * D * D, Wb + (size_t)l * D * D,
        bg + (size_t)l * D, bb + (size_t)l * D, N);
    score_kernel<<<(B + 3) / 4, 256, 0, stream>>>(egob, user, pos, neg, pacc, nacc, B, U, 1);
  }

  reg_kernel<<<(B + 3) / 4, 256, 0, stream>>>(iemb, pos, neg, regs, B);
  final_kernel<<<1, 256, 0, stream>>>(pacc, nacc, regs, (float*)d_out, B);
}

// Round 4
// 1141.679 us; speedup vs baseline: 2.1179x; 1.3688x over previous
//
#include <hip/hip_runtime.h>
#include <math.h>

#define D 128
#define NEG_SLOPE 0.2f
#define REG_LAMBDA 1e-4f
#define NORM_EPS 1e-12f

#define RPB 256          // rows per coarse bucket
#define RPB_SHIFT 8
#define MAXB 1024        // max buckets supported (N <= 262144)
#define CHUNK 4096       // edges per bscatter block

#define XPAD 264         // padded LDS row stride in bf16 elems (256 + 8)

using bf16x8 = __attribute__((ext_vector_type(8))) short;
using f32x4  = __attribute__((ext_vector_type(4))) float;

__device__ __forceinline__ float wave_red(float v){
  #pragma unroll
  for (int o = 32; o > 0; o >>= 1) v += __shfl_xor(v, o, 64);
  return v;
}

__device__ __forceinline__ unsigned short f2bf(float f){
  unsigned int u = __float_as_uint(f);
  unsigned int r = (u + 0x7fffu + ((u >> 16) & 1u)) >> 16;  // RNE
  return (unsigned short)r;
}
__device__ __forceinline__ float bf_lo(unsigned int x){ return __uint_as_float(x << 16); }
__device__ __forceinline__ float bf_hi(unsigned int x){ return __uint_as_float(x & 0xffff0000u); }

// float2 pairs -> packed bf16 (2 per uint)
__global__ __launch_bounds__(256) void tobf16_kernel(const float* __restrict__ src, unsigned int* __restrict__ dst, int npairs){
  int i = blockIdx.x*256 + threadIdx.x;
  if (i >= npairs) return;
  float2 v = ((const float2*)src)[i];
  dst[i] = (unsigned int)f2bf(v.x) | ((unsigned int)f2bf(v.y) << 16);
}

// Convert W_gcn/W_bi (fp32 row-major, L layers) into per-layer MFMA B-fragment
// order, bf16: Wf[l][((ks*8 + t)*64 + lane)*8 + j] = Wc[k][n],
// k = ks*32 + (lane>>4)*8 + j, n = t*16 + (lane&15); Wc = [W1; W2] (256 x 128).
__global__ __launch_bounds__(256) void wconv_kernel(const float* __restrict__ Wg, const float* __restrict__ Wb,
                                                    unsigned short* __restrict__ Wf, int L){
  int idx = blockIdx.x*256 + threadIdx.x;
  int total = L * 256 * D;
  if (idx >= total) return;
  int l = idx >> 15;          // / (256*128)
  int rem = idx & 32767;
  int k = rem >> 7;           // 0..255
  int n = rem & 127;
  float v = (k < 128) ? Wg[((size_t)l*128 + k)*D + n] : Wb[((size_t)l*128 + (k-128))*D + n];
  int ks = k >> 5, quad = (k >> 3) & 3, j = k & 7;
  int t = n >> 4, ln = (quad << 4) | (n & 15);
  Wf[(size_t)l*32768 + (((ks*8 + t)*64 + ln)*8 + j)] = f2bf(v);
}

// K1: coarse bucket histogram, LDS-aggregated
__global__ __launch_bounds__(256) void bhist_kernel(const int* __restrict__ erow, int* __restrict__ bcnt, int nnz, int nbk){
  __shared__ int h[MAXB];
  for (int i = threadIdx.x; i < nbk; i += 256) h[i] = 0;
  __syncthreads();
  int stride = gridDim.x * 256;
  for (int e = blockIdx.x*256 + threadIdx.x; e < nnz; e += stride)
    atomicAdd(&h[erow[e] >> RPB_SHIFT], 1);
  __syncthreads();
  for (int i = threadIdx.x; i < nbk; i += 256){
    int c = h[i];
    if (c) atomicAdd(&bcnt[i], c);
  }
}

// K2: exclusive scan of bucket counts (single block)
__global__ __launch_bounds__(1024) void bscan_kernel(const int* __restrict__ bcnt, int* __restrict__ bbase,
                                                     int* __restrict__ bcur, int* __restrict__ rowptr,
                                                     int nbk, int nnz, int n){
  __shared__ int tmp[1024];
  int t = threadIdx.x;
  int v = (t < nbk) ? bcnt[t] : 0;
  tmp[t] = v; __syncthreads();
  #pragma unroll
  for (int off = 1; off < 1024; off <<= 1){
    int a = (t >= off) ? tmp[t-off] : 0; __syncthreads();
    tmp[t] += a; __syncthreads();
  }
  if (t < nbk){ int b = tmp[t] - v; bbase[t] = b; bcur[t] = b; }
  if (t == 0){ bbase[nbk] = nnz; rowptr[n] = nnz; }
}

// K3: coarse scatter. Block sorts a CHUNK of edges by bucket in LDS, reserves
// global ranges (one atomic per bucket per block), writes coalesced runs.
__global__ __launch_bounds__(256) void bscatter_kernel(const int* __restrict__ erow, const int* __restrict__ ecol,
                                                       const float* __restrict__ eval, int* __restrict__ bcur,
                                                       int2* __restrict__ ebuf, int nnz, int nbk){
  __shared__ int2 ls[CHUNK];
  __shared__ int gdst[CHUNK];
  __shared__ int h[MAXB];
  __shared__ int hx[MAXB];
  __shared__ int tmp[256];
  int tid = threadIdx.x;
  int base = blockIdx.x * CHUNK;
  int cn = min(CHUNK, nnz - base);
  for (int i = tid; i < nbk; i += 256) h[i] = 0;
  __syncthreads();
  for (int i = tid; i < cn; i += 256)
    atomicAdd(&h[erow[base+i] >> RPB_SHIFT], 1);
  __syncthreads();
  int b0 = tid*4;
  int c0=0,c1=0,c2=0,c3=0;
  if (b0 < nbk){
    c0 = h[b0];
    if (b0+1 < nbk) c1 = h[b0+1];
    if (b0+2 < nbk) c2 = h[b0+2];
    if (b0+3 < nbk) c3 = h[b0+3];
  }
  int tsum = c0+c1+c2+c3;
  tmp[tid] = tsum; __syncthreads();
  #pragma unroll
  for (int off = 1; off < 256; off <<= 1){
    int a = (tid >= off) ? tmp[tid-off] : 0; __syncthreads();
    tmp[tid] += a; __syncthreads();
  }
  int tbase = tmp[tid] - tsum;
  if (b0 < nbk){
    hx[b0] = tbase;
    if (b0+1 < nbk) hx[b0+1] = tbase + c0;
    if (b0+2 < nbk) hx[b0+2] = tbase + c0 + c1;
    if (b0+3 < nbk) hx[b0+3] = tbase + c0 + c1 + c2;
  }
  __syncthreads();
  for (int i = tid; i < nbk; i += 256){
    int c = h[i];
    if (c > 0){
      int gb = atomicAdd(&bcur[i], c);
      h[i] = gb - hx[i];
    }
  }
  __syncthreads();
  for (int i = tid; i < cn; i += 256){
    int r = erow[base+i];
    int b = r >> RPB_SHIFT;
    int x = ecol[base+i] | ((r & (RPB-1)) << 20);
    int lpos = atomicAdd(&hx[b], 1);
    ls[lpos] = make_int2(x, __float_as_int(eval[base+i]));
    gdst[lpos] = h[b] + lpos;
  }
  __syncthreads();
  for (int i = tid; i < cn; i += 256)
    ebuf[gdst[i]] = ls[i];
}

// K4: one block per bucket -> rowptr + final CSR (L2-local full-line writes).
__global__ __launch_bounds__(256) void fscatter_kernel(const int2* __restrict__ ebuf, const int* __restrict__ bbase,
                                                       int2* __restrict__ ep, int* __restrict__ rowptr, int n){
  __shared__ int rh[RPB];
  __shared__ int rx[RPB];
  int b = blockIdx.x;
  int tid = threadIdx.x;
  int s = bbase[b], e = bbase[b+1];
  int row0 = b << RPB_SHIFT;
  rh[tid] = 0;
  __syncthreads();
  for (int i = s + tid; i < e; i += 256)
    atomicAdd(&rh[ebuf[i].x >> 20], 1);
  __syncthreads();
  int v = rh[tid];
  rx[tid] = v; __syncthreads();
  #pragma unroll
  for (int off = 1; off < 256; off <<= 1){
    int a = (tid >= off) ? rx[tid-off] : 0; __syncthreads();
    rx[tid] += a; __syncthreads();
  }
  int excl = rx[tid] - v;
  __syncthreads();
  if (row0 + tid < n) rowptr[row0 + tid] = s + excl;
  rh[tid] = s + excl;
  __syncthreads();
  for (int i = s + tid; i < e; i += 256){
    int2 x = ebuf[i];
    int rl = x.x >> 20;
    int p = atomicAdd(&rh[rl], 1);
    ep[p] = make_int2(x.x & 0xFFFFF, x.y);
  }
}

// sideb[r] = bf16( sum_e val_e * ego_bf16[col_e] ) ; one wave per row, fp32 accum.
__global__ __launch_bounds__(256) void spmm_kernel(const int* __restrict__ rowptr, const int2* __restrict__ ep,
                                                   const unsigned int* __restrict__ egob,
                                                   unsigned int* __restrict__ sideb, int n){
  int w = (blockIdx.x*256 + threadIdx.x) >> 6;
  int lane = threadIdx.x & 63;
  if (w >= n) return;
  int s = rowptr[w], e = rowptr[w+1];
  float ax = 0.f, ay = 0.f;
  int i = s;
  for (; i + 3 < e; i += 4){
    int2 e0 = ep[i], e1 = ep[i+1], e2 = ep[i+2], e3 = ep[i+3];
    unsigned int x0 = egob[(size_t)e0.x*64 + lane];
    unsigned int x1 = egob[(size_t)e1.x*64 + lane];
    unsigned int x2 = egob[(size_t)e2.x*64 + lane];
    unsigned int x3 = egob[(size_t)e3.x*64 + lane];
    float v0 = __int_as_float(e0.y), v1 = __int_as_float(e1.y);
    float v2 = __int_as_float(e2.y), v3 = __int_as_float(e3.y);
    ax = fmaf(v0, bf_lo(x0), ax); ay = fmaf(v0, bf_hi(x0), ay);
    ax = fmaf(v1, bf_lo(x1), ax); ay = fmaf(v1, bf_hi(x1), ay);
    ax = fmaf(v2, bf_lo(x2), ax); ay = fmaf(v2, bf_hi(x2), ay);
    ax = fmaf(v3, bf_lo(x3), ax); ay = fmaf(v3, bf_hi(x3), ay);
  }
  for (; i < e; i++){
    int2 e0 = ep[i];
    unsigned int x0 = egob[(size_t)e0.x*64 + lane];
    float v0 = __int_as_float(e0.y);
    ax = fmaf(v0, bf_lo(x0), ax); ay = fmaf(v0, bf_hi(x0), ay);
  }
  sideb[(size_t)w*64 + lane] = (unsigned int)f2bf(ax) | ((unsigned int)f2bf(ay) << 16);
}

// MFMA transform: egob[r] = bf16(leaky( X[r] @ Wc + b1 + b2 )),
// X = [side | ego .* side] (bf16), Wc = [W1; W2] pre-swizzled bf16 (B-frag order).
// Block: 64 rows; 4 waves x 16 rows; 8 col-tiles x 8 k-steps of 16x16x32 MFMA.
__global__ __launch_bounds__(256, 4) void transform_kernel(const unsigned int* __restrict__ sideb,
                                                           unsigned int* __restrict__ egob,
                                                           const unsigned short* __restrict__ Wf,
                                                           const float* __restrict__ b1, const float* __restrict__ b2,
                                                           int n){
  __shared__ __align__(16) unsigned short X[64 * XPAD];   // 33 KB
  int row0 = blockIdx.x * 64;
  int tid = threadIdx.x;
  // stage X: 64 rows x 64 pair-cols
  for (int idx = tid; idx < 64*64; idx += 256){
    int r = idx >> 6, cp = idx & 63;
    int row = row0 + r;
    unsigned int sv = 0, pv = 0;
    if (row < n){
      unsigned int s2 = sideb[(size_t)row*64 + cp];
      unsigned int eb = egob[(size_t)row*64 + cp];
      sv = s2;
      pv = (unsigned int)f2bf(bf_lo(s2) * bf_lo(eb)) | ((unsigned int)f2bf(bf_hi(s2) * bf_hi(eb)) << 16);
    }
    *(unsigned int*)&X[r*XPAD + 2*cp]       = sv;
    *(unsigned int*)&X[r*XPAD + 128 + 2*cp] = pv;
  }
  __syncthreads();

  int wave = tid >> 6, lane = tid & 63;
  int wr0 = wave * 16;
  int m = lane & 15, quad = lane >> 4;

  f32x4 acc[8];
  #pragma unroll
  for (int t = 0; t < 8; t++) acc[t] = (f32x4){0.f, 0.f, 0.f, 0.f};

  const unsigned short* arow = &X[(wr0 + m)*XPAD + quad*8];
  #pragma unroll
  for (int ks = 0; ks < 8; ks++){
    bf16x8 a = *(const bf16x8*)(arow + ks*32);
    #pragma unroll
    for (int t = 0; t < 8; t++){
      bf16x8 b = *(const bf16x8*)&Wf[((ks*8 + t)*64 + lane)*8];
      acc[t] = __builtin_amdgcn_mfma_f32_16x16x32_bf16(a, b, acc[t], 0, 0, 0);
    }
  }

  unsigned short* ego16 = (unsigned short*)egob;
  #pragma unroll
  for (int t = 0; t < 8; t++){
    int col = t*16 + m;
    float bb = b1[col] + b2[col];
    #pragma unroll
    for (int r = 0; r < 4; r++){
      int row = row0 + wr0 + quad*4 + r;
      if (row < n){
        float v = acc[t][r] + bb;
        v = v > 0.f ? v : NEG_SLOPE*v;
        ego16[(size_t)row*D + col] = f2bf(v);
      }
    }
  }
}

// Accumulate per-sample dot contributions of the current block (bf16 base).
__global__ __launch_bounds__(256) void score_kernel(const unsigned int* __restrict__ egob, const int* __restrict__ user,
                                                    const int* __restrict__ pos, const int* __restrict__ neg,
                                                    float* __restrict__ pacc, float* __restrict__ nacc,
                                                    int B, int U, int normalize){
  int w = (blockIdx.x*256 + threadIdx.x) >> 6;
  int lane = threadIdx.x & 63;
  if (w >= B) return;
  size_t ur = (size_t)user[w] * 64;
  size_t pr = ((size_t)U + pos[w]) * 64;
  size_t nr = ((size_t)U + neg[w]) * 64;
  unsigned int ub = egob[ur + lane], pb = egob[pr + lane], nb = egob[nr + lane];
  float ux = bf_lo(ub), uy = bf_hi(ub);
  float px = bf_lo(pb), py = bf_hi(pb);
  float nx = bf_lo(nb), ny = bf_hi(nb);
  float dup = ux*px + uy*py;
  float dun = ux*nx + uy*ny;
  float nu  = ux*ux + uy*uy;
  float np  = px*px + py*py;
  float nn  = nx*nx + ny*ny;
  dup = wave_red(dup); dun = wave_red(dun);
  nu = wave_red(nu); np = wave_red(np); nn = wave_red(nn);
  if (lane == 0){
    if (normalize){
      float inu = 1.f / fmaxf(sqrtf(nu), NORM_EPS);
      float inp = 1.f / fmaxf(sqrtf(np), NORM_EPS);
      float inn = 1.f / fmaxf(sqrtf(nn), NORM_EPS);
      pacc[w] += dup * inu * inp;
      nacc[w] += dun * inu * inn;
    } else {
      pacc[w] += dup;
      nacc[w] += dun;
    }
  }
}

__global__ __launch_bounds__(256) void reg_kernel(const float* __restrict__ item, const int* __restrict__ pos,
                                                  const int* __restrict__ neg, float* __restrict__ reg_out, int B){
  int w = (blockIdx.x*256 + threadIdx.x) >> 6;
  int lane = threadIdx.x & 63;
  if (w >= B) return;
  const float2* it = (const float2*)item;
  float2 pv = it[(size_t)pos[w]*64 + lane];
  float2 nv = it[(size_t)neg[w]*64 + lane];
  float v = pv.x*pv.x + pv.y*pv.y + nv.x*nv.x + nv.y*nv.y;
  v = wave_red(v);
  if (lane == 0) atomicAdd(reg_out, v);
}

__global__ __launch_bounds__(256) void final_kernel(const float* __restrict__ pacc, const float* __restrict__ nacc,
                                                    const float* __restrict__ reg_sum, float* __restrict__ out, int B){
  __shared__ float red[256];
  float s = 0.f;
  for (int i = threadIdx.x; i < B; i += 256){
    float x = nacc[i] - pacc[i];
    s += (x > 0.f) ? x + log1pf(expf(-x)) : log1pf(expf(x));   // softplus, stable
  }
  red[threadIdx.x] = s; __syncthreads();
  for (int o = 128; o > 0; o >>= 1){
    if (threadIdx.x < o) red[threadIdx.x] += red[threadIdx.x + o];
    __syncthreads();
  }
  if (threadIdx.x == 0){
    out[0] = red[0] / (float)B;
    out[1] = REG_LAMBDA * 0.5f * reg_sum[0] / (float)B;
  }
}

extern "C" void kernel_launch(void* const* d_in, const int* in_sizes, int n_in,
                              void* d_out, int out_size, void* d_ws, size_t ws_size,
                              hipStream_t stream) {
  const int*   user = (const int*)d_in[0];
  const int*   pos  = (const int*)d_in[1];
  const int*   neg  = (const int*)d_in[2];
  const int*   erow = (const int*)d_in[3];
  const int*   ecol = (const int*)d_in[4];
  const float* eval = (const float*)d_in[5];
  const float* uemb = (const float*)d_in[6];
  const float* iemb = (const float*)d_in[7];
  const float* Wg   = (const float*)d_in[8];
  const float* bg   = (const float*)d_in[9];
  const float* Wb   = (const float*)d_in[10];
  const float* bb   = (const float*)d_in[11];

  int B   = in_sizes[0];
  int NNZ = in_sizes[3];
  int U   = in_sizes[6] / D;
  int I   = in_sizes[7] / D;
  int N   = U + I;
  int L   = in_sizes[9] / D;
  int nbk = (N + RPB - 1) >> RPB_SHIFT;

  char* wsp = (char*)d_ws;
  auto alloc = [&](size_t bytes) -> char* {
    char* p = wsp; wsp += (bytes + 255) & ~(size_t)255; return p;
  };
  size_t side_bytes = (size_t)N * D * 2;
  size_t ebuf_bytes = (size_t)NNZ * 8;
  unsigned int*  sideb  = (unsigned int*)alloc(side_bytes > ebuf_bytes ? side_bytes : ebuf_bytes);
  unsigned int*  egob   = (unsigned int*)alloc((size_t)N * D * 2);     // bf16 ego, pair-packed
  int2*          ep     = (int2*) alloc((size_t)NNZ * 8);              // final CSR (col, val)
  unsigned short* Wf    = (unsigned short*)alloc((size_t)L * 256 * D * 2);
  int*           rowptr = (int*)  alloc((size_t)(N + 1) * 4);
  int*           bcnt   = (int*)  alloc((size_t)MAXB * 4);
  int*           bbase  = (int*)  alloc((size_t)(MAXB + 1) * 4);
  int*           bcur   = (int*)  alloc((size_t)MAXB * 4);
  float*         pacc   = (float*)alloc((size_t)B * 4);
  float*         nacc   = (float*)alloc((size_t)B * 4);
  float*         regs   = (float*)alloc(256);
  int2*          ebuf   = (int2*)sideb;   // staging alias (used only during build)

  hipMemsetAsync(bcnt, 0, (size_t)nbk * 4, stream);
  hipMemsetAsync(pacc, 0, (size_t)B * 4, stream);
  hipMemsetAsync(nacc, 0, (size_t)B * 4, stream);
  hipMemsetAsync(regs, 0, 4, stream);

  // bf16 ego directly from input embeddings; W pre-swizzle
  tobf16_kernel<<<(U*64 + 255) / 256, 256, 0, stream>>>(uemb, egob, U*64);
  tobf16_kernel<<<(I*64 + 255) / 256, 256, 0, stream>>>(iemb, egob + (size_t)U*64, I*64);
  wconv_kernel<<<(L*256*D + 255) / 256, 256, 0, stream>>>(Wg, Wb, Wf, L);

  // Bucketed CSR build
  bhist_kernel<<<2048, 256, 0, stream>>>(erow, bcnt, NNZ, nbk);
  bscan_kernel<<<1, 1024, 0, stream>>>(bcnt, bbase, bcur, rowptr, nbk, NNZ, N);
  bscatter_kernel<<<(NNZ + CHUNK - 1) / CHUNK, 256, 0, stream>>>(erow, ecol, eval, bcur, ebuf, NNZ, nbk);
  fscatter_kernel<<<nbk, 256, 0, stream>>>(ebuf, bbase, ep, rowptr, N);

  // Block 0 (raw embeddings, un-normalized)
  score_kernel<<<(B + 3) / 4, 256, 0, stream>>>(egob, user, pos, neg, pacc, nacc, B, U, 0);

  for (int l = 0; l < L; l++){
    spmm_kernel<<<(N + 3) / 4, 256, 0, stream>>>(rowptr, ep, egob, sideb, N);
    transform_kernel<<<(N + 63) / 64, 256, 0, stream>>>(
        sideb, egob, Wf + (size_t)l * 256 * D,
        bg + (size_t)l * D, bb + (size_t)l * D, N);
    score_kernel<<<(B + 3) / 4, 256, 0, stream>>>(egob, user, pos, neg, pacc, nacc, B, U, 1);
  }

  reg_kernel<<<(B + 3) / 4, 256, 0, stream>>>(iemb, pos, neg, regs, B);
  final_kernel<<<1, 256, 0, stream>>>(pacc, nacc, regs, (float*)d_out, B);
}